// Round 5
// baseline (1788.329 us; speedup 1.0000x reference)
//
#include <hip/hip_runtime.h>

// VQ nearest-codebook argmin — two-pass architecture.
//
// Pass 1 (fast): fp32 tiled GEMM, per-row best + runner-up of v = s2 - 2*z.e.
//   Rows with (second-best - best) <= TAU are flagged. For unflagged rows the
//   winner leads by more than the reference's total fp32-quantization slack
//   (<= ~6.2e-5 pairwise), so pass-1's argmin == numpy's argmin.
// Pass 2 (exact, round-3 kernel verbatim, validated absmax 0): for flagged
//   rows only, full numpy-fp32 bit-semantics emulation over all 1024 codes:
//     s1,s2 = numpy pairwise fp32 sums of squares; G = fp64 dot -> fl32(2G);
//     d = fl32(fl32(s1-2G)+s2); argmin, ties -> lowest index.

#define DDIM 256
#define KCODES 1024
#define BM 64          // rows per pass-1 block
#define BN 128         // codes in flight per ct-tile
#define BK 32          // k-step
#define NCT (KCODES / BN)    // 8
#define NTILES (NCT * 8)     // 64  (8 ks-steps per ct)
#define STA 68         // At row stride (floats): [kk][row0..63]+pad
#define STB 132        // Bt row stride (floats): [kk][code0..127]+pad
#define TAU 1e-4f

// ---------- locked numerics helpers (rounds 3/4, do not touch) ----------
__device__ __forceinline__ float block128_sq(const float* __restrict__ a)
{
#pragma clang fp contract(off)
    float r[8];
    #pragma unroll
    for (int j = 0; j < 8; ++j) { float v = a[j]; r[j] = v * v; }
    #pragma unroll
    for (int i = 8; i < 128; i += 8) {
        #pragma unroll
        for (int j = 0; j < 8; ++j) { float v = a[i + j]; r[j] = r[j] + v * v; }
    }
    return ((r[0] + r[1]) + (r[2] + r[3])) + ((r[4] + r[5]) + (r[6] + r[7]));
}

__device__ __forceinline__ float block128_sq_dot(
    const float* __restrict__ a, const float* __restrict__ zz, double& dot)
{
#pragma clang fp contract(off)
    float r[8];
    #pragma unroll
    for (int j = 0; j < 8; ++j) {
        float v = a[j];
        float sq = v * v;
        r[j] = sq;
        dot = fma((double)zz[j], (double)v, dot);
    }
    #pragma unroll
    for (int i = 8; i < 128; i += 8) {
        #pragma unroll
        for (int j = 0; j < 8; ++j) {
            float v = a[i + j];
            float sq = v * v;
            r[j] = r[j] + sq;
            dot = fma((double)zz[i + j], (double)v, dot);
        }
    }
    return ((r[0] + r[1]) + (r[2] + r[3])) + ((r[4] + r[5]) + (r[6] + r[7]));
}

__global__ __launch_bounds__(256) void vq_s2_kernel(
    const float* __restrict__ emb, float* __restrict__ s2)
{
    const int k = blockIdx.x * 256 + threadIdx.x;
    if (k < KCODES) {
        const float* e = emb + (size_t)k * DDIM;
        s2[k] = block128_sq(e) + block128_sq(e + 128);
    }
}

// ---------------------------- pass 1 ----------------------------
__global__ __launch_bounds__(128) void vq_pass1(
    const float* __restrict__ z, const float* __restrict__ emb,
    const float* __restrict__ s2g, int* __restrict__ out,
    unsigned char* __restrict__ flag, int N)
{
    __shared__ float At[2][BK][STA];   // A^T tile: [kk][row], 2 buffers
    __shared__ float Bt[2][BK][STB];   // B^T tile: [kk][code], 2 buffers

    const int tid  = threadIdx.x;
    const int ty   = tid >> 4;     // 0..7  -> rows  {ty*4+j, 32+ty*4+j}
    const int tc   = tid & 15;     // 0..15 -> codes {tc*4+i, 64+tc*4+i}
    const int row0 = blockIdx.x * BM;

    float4 ra[4], rb[8];           // reg staging for next tile

    float acc[8][8];
    float bv[8], sv[8];
    int   bk_[8];
    #pragma unroll
    for (int j = 0; j < 8; ++j) { bv[j] = 3.4e38f; sv[j] = 3.4e38f; bk_[j] = 0; }

    // --- stage tile 0 ---
    {
        const int ct = 0, ks = 0;
        #pragma unroll
        for (int it = 0; it < 4; ++it) {
            int f4 = it * 128 + tid, r = f4 >> 3, k4 = f4 & 7;
            ra[it] = *reinterpret_cast<const float4*>(
                z + (size_t)(row0 + r) * DDIM + ks * BK + k4 * 4);
        }
        #pragma unroll
        for (int it = 0; it < 8; ++it) {
            int f4 = it * 128 + tid, c = f4 >> 3, k4 = f4 & 7;
            rb[it] = *reinterpret_cast<const float4*>(
                emb + (size_t)(ct * BN + c) * DDIM + ks * BK + k4 * 4);
        }
        #pragma unroll
        for (int it = 0; it < 4; ++it) {
            int f4 = it * 128 + tid, r = f4 >> 3, k4 = f4 & 7;
            At[0][k4 * 4 + 0][r] = ra[it].x; At[0][k4 * 4 + 1][r] = ra[it].y;
            At[0][k4 * 4 + 2][r] = ra[it].z; At[0][k4 * 4 + 3][r] = ra[it].w;
        }
        #pragma unroll
        for (int it = 0; it < 8; ++it) {
            int f4 = it * 128 + tid, c = f4 >> 3, k4 = f4 & 7;
            Bt[0][k4 * 4 + 0][c] = rb[it].x; Bt[0][k4 * 4 + 1][c] = rb[it].y;
            Bt[0][k4 * 4 + 2][c] = rb[it].z; Bt[0][k4 * 4 + 3][c] = rb[it].w;
        }
    }
    __syncthreads();

    for (int t = 0; t < NTILES; ++t) {
        const int buf = t & 1;

        // issue next tile's global loads (latency hides under compute)
        if (t + 1 < NTILES) {
            const int ct = (t + 1) >> 3, ks = (t + 1) & 7;
            #pragma unroll
            for (int it = 0; it < 4; ++it) {
                int f4 = it * 128 + tid, r = f4 >> 3, k4 = f4 & 7;
                ra[it] = *reinterpret_cast<const float4*>(
                    z + (size_t)(row0 + r) * DDIM + ks * BK + k4 * 4);
            }
            #pragma unroll
            for (int it = 0; it < 8; ++it) {
                int f4 = it * 128 + tid, c = f4 >> 3, k4 = f4 & 7;
                rb[it] = *reinterpret_cast<const float4*>(
                    emb + (size_t)(ct * BN + c) * DDIM + ks * BK + k4 * 4);
            }
        }

        if ((t & 7) == 0) {
            #pragma unroll
            for (int j = 0; j < 8; ++j)
                #pragma unroll
                for (int i = 0; i < 8; ++i) acc[j][i] = 0.0f;
        }

        #pragma unroll
        for (int kk = 0; kk < BK; ++kk) {
            float a[8], b[8];
            *reinterpret_cast<float4*>(&a[0]) =
                *reinterpret_cast<const float4*>(&At[buf][kk][ty * 4]);
            *reinterpret_cast<float4*>(&a[4]) =
                *reinterpret_cast<const float4*>(&At[buf][kk][32 + ty * 4]);
            *reinterpret_cast<float4*>(&b[0]) =
                *reinterpret_cast<const float4*>(&Bt[buf][kk][tc * 4]);
            *reinterpret_cast<float4*>(&b[4]) =
                *reinterpret_cast<const float4*>(&Bt[buf][kk][64 + tc * 4]);
            #pragma unroll
            for (int j = 0; j < 8; ++j)
                #pragma unroll
                for (int i = 0; i < 8; ++i)
                    acc[j][i] = fmaf(a[j], b[i], acc[j][i]);
        }

        if ((t & 7) == 7) {                     // end of ct-tile: fold top-2
            const int ct = t >> 3;
            #pragma unroll
            for (int i = 0; i < 8; ++i) {
                const int c = ct * BN + (i < 4 ? tc * 4 + i : 64 + tc * 4 + (i - 4));
                const float s2v = s2g[c];
                #pragma unroll
                for (int j = 0; j < 8; ++j) {
                    float v = fmaf(-2.0f, acc[j][i], s2v);
                    if (v < bv[j] || (v == bv[j] && c < bk_[j])) {
                        sv[j] = bv[j]; bv[j] = v; bk_[j] = c;
                    } else {
                        sv[j] = fminf(sv[j], v);
                    }
                }
            }
        }

        if (t + 1 < NTILES) {                   // write next tile into other buf
            const int nb = buf ^ 1;
            #pragma unroll
            for (int it = 0; it < 4; ++it) {
                int f4 = it * 128 + tid, r = f4 >> 3, k4 = f4 & 7;
                At[nb][k4 * 4 + 0][r] = ra[it].x; At[nb][k4 * 4 + 1][r] = ra[it].y;
                At[nb][k4 * 4 + 2][r] = ra[it].z; At[nb][k4 * 4 + 3][r] = ra[it].w;
            }
            #pragma unroll
            for (int it = 0; it < 8; ++it) {
                int f4 = it * 128 + tid, c = f4 >> 3, k4 = f4 & 7;
                Bt[nb][k4 * 4 + 0][c] = rb[it].x; Bt[nb][k4 * 4 + 1][c] = rb[it].y;
                Bt[nb][k4 * 4 + 2][c] = rb[it].z; Bt[nb][k4 * 4 + 3][c] = rb[it].w;
            }
        }
        __syncthreads();
    }

    // reduce (bv,bk,sv) across the 16 tc lanes (xor 1,2,4,8 stays within ty)
    #pragma unroll
    for (int off = 1; off < 16; off <<= 1) {
        #pragma unroll
        for (int j = 0; j < 8; ++j) {
            float ob = __shfl_xor(bv[j], off, 64);
            int   ok = __shfl_xor(bk_[j], off, 64);
            float os = __shfl_xor(sv[j], off, 64);
            if (ob < bv[j] || (ob == bv[j] && ok < bk_[j])) {
                sv[j] = fminf(bv[j], os); bv[j] = ob; bk_[j] = ok;
            } else {
                sv[j] = fminf(sv[j], ob);
            }
        }
    }

    if (tc == 0) {
        #pragma unroll
        for (int j = 0; j < 8; ++j) {
            int r = row0 + (j < 4 ? ty * 4 + j : 32 + ty * 4 + (j - 4));
            if (r < N) {
                out[r]  = bk_[j];
                flag[r] = (sv[j] - bv[j] <= TAU) ? 1 : 0;
            }
        }
    }
}

// ------------------- pass 2: exact rescore (round-3 body) -------------------
__global__ __launch_bounds__(256) void vq_pass2(
    const float* __restrict__ z, const float* __restrict__ emb,
    const unsigned char* __restrict__ flag, int* __restrict__ out, int N)
{
#pragma clang fp contract(off)
    __shared__ float zrow[4][DDIM];

    const int wic  = threadIdx.x >> 6;
    const int lane = threadIdx.x & 63;
    const int row  = blockIdx.x * 4 + wic;
    const bool active = (row < N) && (flag[row] != 0);

    if (active) {
        for (int d = lane; d < DDIM; d += 64)
            zrow[wic][d] = z[(size_t)row * DDIM + d];
    }
    __syncthreads();
    if (!active) return;

    const float* zr = zrow[wic];
    const float s1 = block128_sq(zr) + block128_sq(zr + 128);

    float bestv = 3.4e38f;
    int   bestk = 0;

    for (int kk = 0; kk < KCODES / 64; ++kk) {
        const int k = kk * 64 + lane;
        const float* __restrict__ e = emb + (size_t)k * DDIM;

        double dot = 0.0;
        float b0 = block128_sq_dot(e,       zr,       dot);
        float b1 = block128_sq_dot(e + 128, zr + 128, dot);
        float s2 = b0 + b1;

        float twog = 2.0f * (float)dot;
        float t1   = s1 - twog;
        float d    = t1 + s2;

        if (d < bestv || (d == bestv && k < bestk)) { bestv = d; bestk = k; }
    }

    #pragma unroll
    for (int off = 1; off < 64; off <<= 1) {
        float ov = __shfl_xor(bestv, off, 64);
        int   ok = __shfl_xor(bestk, off, 64);
        if (ov < bestv || (ov == bestv && ok < bestk)) { bestv = ov; bestk = ok; }
    }

    if (lane == 0) out[row] = bestk;
}

extern "C" void kernel_launch(void* const* d_in, const int* in_sizes, int n_in,
                              void* d_out, int out_size, void* d_ws, size_t ws_size,
                              hipStream_t stream) {
    const float* z   = (const float*)d_in[0];
    const float* emb = (const float*)d_in[1];
    int*   out  = (int*)d_out;
    float* s2   = (float*)d_ws;                                  // 4 KB
    unsigned char* flag = (unsigned char*)d_ws + 4096;           // 32 KB
    const int N = in_sizes[0] / DDIM;                            // 32768

    vq_s2_kernel<<<dim3((KCODES + 255) / 256), dim3(256), 0, stream>>>(emb, s2);
    vq_pass1<<<dim3((N + BM - 1) / BM), dim3(128), 0, stream>>>(z, emb, s2, out, flag, N);
    vq_pass2<<<dim3((N + 3) / 4), dim3(256), 0, stream>>>(z, emb, flag, out, N);
}

// Round 6
// 361.598 us; speedup vs baseline: 4.9456x; 4.9456x over previous
//
#include <hip/hip_runtime.h>

// VQ nearest-codebook argmin — two-pass, compacted rescore.
//
// Pass 1 (fast): fp32 tiled GEMM, per-row best + runner-up of v = s2 - 2*z.e.
//   Rows with (runnerup - best) <= TAU get appended to a compacted list
//   (atomicAdd). Unflagged rows: winner leads by more than the reference's
//   total fp32-quantization slack (~7.6e-5 < TAU=1e-4) -> matches numpy.
// Pass 2 (exact, locked numerics from round 3, absmax 0): one block per
//   flagged row; fp64 dots, d = fl32(fl32(s1-2G)+s2), first-index argmin.

#define DDIM 256
#define KCODES 1024
#define BM 64
#define BN 128
#define BK 32
#define NCT (KCODES / BN)    // 8
#define NTILES (NCT * 8)     // 64
#define STA 68
#define STB 132
#define TAU 1e-4f
#define LISTCAP 16384

// ---------- locked numerics helper (rounds 3/4/5, do not touch) ----------
__device__ __forceinline__ float block128_sq(const float* __restrict__ a)
{
#pragma clang fp contract(off)
    float r[8];
    #pragma unroll
    for (int j = 0; j < 8; ++j) { float v = a[j]; r[j] = v * v; }
    #pragma unroll
    for (int i = 8; i < 128; i += 8) {
        #pragma unroll
        for (int j = 0; j < 8; ++j) { float v = a[i + j]; r[j] = r[j] + v * v; }
    }
    return ((r[0] + r[1]) + (r[2] + r[3])) + ((r[4] + r[5]) + (r[6] + r[7]));
}

__global__ __launch_bounds__(256) void vq_s2_kernel(
    const float* __restrict__ emb, float* __restrict__ s2, int* __restrict__ count)
{
    if (blockIdx.x == 0 && threadIdx.x == 0) *count = 0;   // reset for this launch
    const int k = blockIdx.x * 256 + threadIdx.x;
    if (k < KCODES) {
        const float* e = emb + (size_t)k * DDIM;
        s2[k] = block128_sq(e) + block128_sq(e + 128);
    }
}

// ---------------------------- pass 1 (unchanged GEMM) ----------------------------
__global__ __launch_bounds__(128) void vq_pass1(
    const float* __restrict__ z, const float* __restrict__ emb,
    const float* __restrict__ s2g, int* __restrict__ out,
    int* __restrict__ count, int* __restrict__ list, int N)
{
    __shared__ float At[2][BK][STA];
    __shared__ float Bt[2][BK][STB];

    const int tid  = threadIdx.x;
    const int ty   = tid >> 4;
    const int tc   = tid & 15;
    const int row0 = blockIdx.x * BM;

    float4 ra[4], rb[8];

    float acc[8][8];
    float bv[8], sv[8];
    int   bk_[8];
    #pragma unroll
    for (int j = 0; j < 8; ++j) { bv[j] = 3.4e38f; sv[j] = 3.4e38f; bk_[j] = 0; }

    {
        const int ct = 0, ks = 0;
        #pragma unroll
        for (int it = 0; it < 4; ++it) {
            int f4 = it * 128 + tid, r = f4 >> 3, k4 = f4 & 7;
            ra[it] = *reinterpret_cast<const float4*>(
                z + (size_t)(row0 + r) * DDIM + ks * BK + k4 * 4);
        }
        #pragma unroll
        for (int it = 0; it < 8; ++it) {
            int f4 = it * 128 + tid, c = f4 >> 3, k4 = f4 & 7;
            rb[it] = *reinterpret_cast<const float4*>(
                emb + (size_t)(ct * BN + c) * DDIM + ks * BK + k4 * 4);
        }
        #pragma unroll
        for (int it = 0; it < 4; ++it) {
            int f4 = it * 128 + tid, r = f4 >> 3, k4 = f4 & 7;
            At[0][k4 * 4 + 0][r] = ra[it].x; At[0][k4 * 4 + 1][r] = ra[it].y;
            At[0][k4 * 4 + 2][r] = ra[it].z; At[0][k4 * 4 + 3][r] = ra[it].w;
        }
        #pragma unroll
        for (int it = 0; it < 8; ++it) {
            int f4 = it * 128 + tid, c = f4 >> 3, k4 = f4 & 7;
            Bt[0][k4 * 4 + 0][c] = rb[it].x; Bt[0][k4 * 4 + 1][c] = rb[it].y;
            Bt[0][k4 * 4 + 2][c] = rb[it].z; Bt[0][k4 * 4 + 3][c] = rb[it].w;
        }
    }
    __syncthreads();

    for (int t = 0; t < NTILES; ++t) {
        const int buf = t & 1;

        if (t + 1 < NTILES) {
            const int ct = (t + 1) >> 3, ks = (t + 1) & 7;
            #pragma unroll
            for (int it = 0; it < 4; ++it) {
                int f4 = it * 128 + tid, r = f4 >> 3, k4 = f4 & 7;
                ra[it] = *reinterpret_cast<const float4*>(
                    z + (size_t)(row0 + r) * DDIM + ks * BK + k4 * 4);
            }
            #pragma unroll
            for (int it = 0; it < 8; ++it) {
                int f4 = it * 128 + tid, c = f4 >> 3, k4 = f4 & 7;
                rb[it] = *reinterpret_cast<const float4*>(
                    emb + (size_t)(ct * BN + c) * DDIM + ks * BK + k4 * 4);
            }
        }

        if ((t & 7) == 0) {
            #pragma unroll
            for (int j = 0; j < 8; ++j)
                #pragma unroll
                for (int i = 0; i < 8; ++i) acc[j][i] = 0.0f;
        }

        #pragma unroll
        for (int kk = 0; kk < BK; ++kk) {
            float a[8], b[8];
            *reinterpret_cast<float4*>(&a[0]) =
                *reinterpret_cast<const float4*>(&At[buf][kk][ty * 4]);
            *reinterpret_cast<float4*>(&a[4]) =
                *reinterpret_cast<const float4*>(&At[buf][kk][32 + ty * 4]);
            *reinterpret_cast<float4*>(&b[0]) =
                *reinterpret_cast<const float4*>(&Bt[buf][kk][tc * 4]);
            *reinterpret_cast<float4*>(&b[4]) =
                *reinterpret_cast<const float4*>(&Bt[buf][kk][64 + tc * 4]);
            #pragma unroll
            for (int j = 0; j < 8; ++j)
                #pragma unroll
                for (int i = 0; i < 8; ++i)
                    acc[j][i] = fmaf(a[j], b[i], acc[j][i]);
        }

        if ((t & 7) == 7) {
            const int ct = t >> 3;
            #pragma unroll
            for (int i = 0; i < 8; ++i) {
                const int c = ct * BN + (i < 4 ? tc * 4 + i : 64 + tc * 4 + (i - 4));
                const float s2v = s2g[c];
                #pragma unroll
                for (int j = 0; j < 8; ++j) {
                    float v = fmaf(-2.0f, acc[j][i], s2v);
                    if (v < bv[j] || (v == bv[j] && c < bk_[j])) {
                        sv[j] = bv[j]; bv[j] = v; bk_[j] = c;
                    } else {
                        sv[j] = fminf(sv[j], v);
                    }
                }
            }
        }

        if (t + 1 < NTILES) {
            const int nb = buf ^ 1;
            #pragma unroll
            for (int it = 0; it < 4; ++it) {
                int f4 = it * 128 + tid, r = f4 >> 3, k4 = f4 & 7;
                At[nb][k4 * 4 + 0][r] = ra[it].x; At[nb][k4 * 4 + 1][r] = ra[it].y;
                At[nb][k4 * 4 + 2][r] = ra[it].z; At[nb][k4 * 4 + 3][r] = ra[it].w;
            }
            #pragma unroll
            for (int it = 0; it < 8; ++it) {
                int f4 = it * 128 + tid, c = f4 >> 3, k4 = f4 & 7;
                Bt[nb][k4 * 4 + 0][c] = rb[it].x; Bt[nb][k4 * 4 + 1][c] = rb[it].y;
                Bt[nb][k4 * 4 + 2][c] = rb[it].z; Bt[nb][k4 * 4 + 3][c] = rb[it].w;
            }
        }
        __syncthreads();
    }

    #pragma unroll
    for (int off = 1; off < 16; off <<= 1) {
        #pragma unroll
        for (int j = 0; j < 8; ++j) {
            float ob = __shfl_xor(bv[j], off, 64);
            int   ok = __shfl_xor(bk_[j], off, 64);
            float os = __shfl_xor(sv[j], off, 64);
            if (ob < bv[j] || (ob == bv[j] && ok < bk_[j])) {
                sv[j] = fminf(bv[j], os); bv[j] = ob; bk_[j] = ok;
            } else {
                sv[j] = fminf(sv[j], ob);
            }
        }
    }

    if (tc == 0) {
        #pragma unroll
        for (int j = 0; j < 8; ++j) {
            int r = row0 + (j < 4 ? ty * 4 + j : 32 + ty * 4 + (j - 4));
            if (r < N) {
                out[r] = bk_[j];
                if (sv[j] - bv[j] <= TAU) {
                    int pos = atomicAdd(count, 1);
                    if (pos < LISTCAP) list[pos] = r;
                }
            }
        }
    }
}

// ------- pass 2: exact rescore, one block per flagged row (locked numerics) -------
__global__ __launch_bounds__(256) void vq_pass2(
    const float* __restrict__ z, const float* __restrict__ emb,
    const float* __restrict__ s2g, const int* __restrict__ count,
    const int* __restrict__ list, int* __restrict__ out)
{
#pragma clang fp contract(off)
    __shared__ float zrow[DDIM];
    __shared__ float s1sh;
    __shared__ float bvw[4];
    __shared__ int   bkw[4];

    const int tid  = threadIdx.x;
    const int lane = tid & 63;
    const int wid  = tid >> 6;
    int cnt = *count; if (cnt > LISTCAP) cnt = LISTCAP;

    for (int idx = blockIdx.x; idx < cnt; idx += gridDim.x) {
        const int row = list[idx];

        if (tid < 64)
            *reinterpret_cast<float4*>(&zrow[tid * 4]) =
                *reinterpret_cast<const float4*>(z + (size_t)row * DDIM + tid * 4);
        __syncthreads();
        if (tid == 0) s1sh = block128_sq(zrow) + block128_sq(zrow + 128);
        __syncthreads();
        const float s1 = s1sh;

        float bestv = 3.4e38f;
        int   bestk = 0;
        #pragma unroll
        for (int i = 0; i < 4; ++i) {
            const int c = tid * 4 + i;                 // contiguous, ascending
            const float* __restrict__ e = emb + (size_t)c * DDIM;
            double dot = 0.0;
            #pragma unroll 8
            for (int d4 = 0; d4 < DDIM / 4; ++d4) {
                float4 ev = *reinterpret_cast<const float4*>(e + d4 * 4);
                const float4 zv = *reinterpret_cast<const float4*>(&zrow[d4 * 4]);
                dot = fma((double)zv.x, (double)ev.x, dot);
                dot = fma((double)zv.y, (double)ev.y, dot);
                dot = fma((double)zv.z, (double)ev.z, dot);
                dot = fma((double)zv.w, (double)ev.w, dot);
            }
            float twog = 2.0f * (float)dot;
            float t1   = s1 - twog;
            float dv   = t1 + s2g[c];
            if (dv < bestv || (dv == bestv && c < bestk)) { bestv = dv; bestk = c; }
        }

        #pragma unroll
        for (int off = 1; off < 64; off <<= 1) {
            float ov = __shfl_xor(bestv, off, 64);
            int   ok = __shfl_xor(bestk, off, 64);
            if (ov < bestv || (ov == bestv && ok < bestk)) { bestv = ov; bestk = ok; }
        }
        if (lane == 0) { bvw[wid] = bestv; bkw[wid] = bestk; }
        __syncthreads();
        if (tid == 0) {
            float bb = bvw[0]; int kb = bkw[0];
            #pragma unroll
            for (int w = 1; w < 4; ++w)
                if (bvw[w] < bb || (bvw[w] == bb && bkw[w] < kb)) { bb = bvw[w]; kb = bkw[w]; }
            out[row] = kb;
        }
        __syncthreads();   // protect zrow/s1sh before next grid-stride row
    }
}

extern "C" void kernel_launch(void* const* d_in, const int* in_sizes, int n_in,
                              void* d_out, int out_size, void* d_ws, size_t ws_size,
                              hipStream_t stream) {
    const float* z   = (const float*)d_in[0];
    const float* emb = (const float*)d_in[1];
    int*   out   = (int*)d_out;
    float* s2    = (float*)d_ws;                                   // 4 KB
    int*   count = (int*)((char*)d_ws + 4096);                     // 128 B slot
    int*   list  = (int*)((char*)d_ws + 4096 + 128);               // 64 KB
    const int N = in_sizes[0] / DDIM;                              // 32768

    vq_s2_kernel<<<dim3((KCODES + 255) / 256), dim3(256), 0, stream>>>(emb, s2, count);
    vq_pass1<<<dim3((N + BM - 1) / BM), dim3(128), 0, stream>>>(z, emb, s2, out, count, list, N);
    vq_pass2<<<dim3(1024), dim3(256), 0, stream>>>(z, emb, s2, count, list, out);
}

// Round 7
// 297.543 us; speedup vs baseline: 6.0103x; 1.2153x over previous
//
#include <hip/hip_runtime.h>

// VQ nearest-codebook argmin — MFMA pass-1 (bf16 hi/lo split) + exact rescore.
//
// Pass 1: G = z.e via 3 bf16 MFMAs (zh*eh + zh*el + zl*eh), fp32 acc.
//   |2G error| <= ~2e-5. Rows with top-2 gap <= TAU_MFMA=2e-4 get rescored.
// Pass 2 (LOCKED numerics, rounds 3-6, absmax 0): numpy-fp32 bit semantics:
//   s1,s2 pairwise fp32 sums of squares; G fp64 -> fl32(2G);
//   d = fl32(fl32(s1-2G)+s2); argmin, first-index tie-break.

#define DDIM 256
#define KCODES 1024
#define TAU_MFMA 2e-4f
#define TAU_OLD  1e-4f
#define LISTCAP 16384

typedef __attribute__((ext_vector_type(8))) short bf16x8;
typedef __attribute__((ext_vector_type(4))) float f32x4;
typedef __attribute__((ext_vector_type(8))) unsigned short u16x8;

// ---------------- bf16 helpers (RNE, bit-exact) ----------------
__device__ __forceinline__ unsigned short f2bf(float f) {
    unsigned int u = __builtin_bit_cast(unsigned int, f);
    u += 0x7FFFu + ((u >> 16) & 1u);
    return (unsigned short)(u >> 16);
}
__device__ __forceinline__ float bf2f(unsigned short h) {
    unsigned int u = ((unsigned int)h) << 16;
    return __builtin_bit_cast(float, u);
}

// ---------- locked numerics helper (rounds 3-6, do not touch) ----------
__device__ __forceinline__ float block128_sq(const float* __restrict__ a)
{
#pragma clang fp contract(off)
    float r[8];
    #pragma unroll
    for (int j = 0; j < 8; ++j) { float v = a[j]; r[j] = v * v; }
    #pragma unroll
    for (int i = 8; i < 128; i += 8) {
        #pragma unroll
        for (int j = 0; j < 8; ++j) { float v = a[i + j]; r[j] = r[j] + v * v; }
    }
    return ((r[0] + r[1]) + (r[2] + r[3])) + ((r[4] + r[5]) + (r[6] + r[7]));
}

__global__ __launch_bounds__(256) void vq_s2_kernel(
    const float* __restrict__ emb, float* __restrict__ s2, int* __restrict__ count)
{
    if (blockIdx.x == 0 && threadIdx.x == 0) *count = 0;
    const int k = blockIdx.x * 256 + threadIdx.x;
    if (k < KCODES) {
        const float* e = emb + (size_t)k * DDIM;
        s2[k] = block128_sq(e) + block128_sq(e + 128);
    }
}

// ---------------- emb -> bf16 hi/lo (linear [code][k]) ----------------
__global__ __launch_bounds__(256) void vq_convert(
    const float* __restrict__ emb,
    unsigned short* __restrict__ eh, unsigned short* __restrict__ el)
{
    const int id = blockIdx.x * 256 + threadIdx.x;     // ushort8 chunk id
    if (id >= KCODES * DDIM / 8) return;
    const float* src = emb + (size_t)id * 8;
    float4 p0 = *reinterpret_cast<const float4*>(src);
    float4 p1 = *reinterpret_cast<const float4*>(src + 4);
    float fv[8] = {p0.x, p0.y, p0.z, p0.w, p1.x, p1.y, p1.z, p1.w};
    u16x8 vh, vl;
    #pragma unroll
    for (int e = 0; e < 8; ++e) {
        unsigned short h = f2bf(fv[e]);
        vh[e] = h;
        vl[e] = f2bf(fv[e] - bf2f(h));
    }
    *reinterpret_cast<u16x8*>(eh + (size_t)id * 8) = vh;
    *reinterpret_cast<u16x8*>(el + (size_t)id * 8) = vl;
}

// ---------------- pass-1 staging helpers ----------------
// B tile: [which hi/lo][128 codes][32 bf16], chunk swizzle pc_phys = c ^ ((code>>1)&3)
__device__ __forceinline__ void stage_issue(
    const unsigned short* __restrict__ eh, const unsigned short* __restrict__ el,
    int ct, int ks, int tid, u16x8* sb)
{
    #pragma unroll
    for (int q = 0; q < 8; ++q) {
        int id = q * 128 + tid;
        int which = id >> 9, cl = (id >> 2) & 127, pc = id & 3;
        int clog = pc ^ ((cl >> 1) & 3);
        const unsigned short* src = (which ? el : eh)
            + (size_t)(ct * 128 + cl) * DDIM + ks * 32 + clog * 8;
        sb[q] = *reinterpret_cast<const u16x8*>(src);
    }
}
__device__ __forceinline__ void stage_write(
    unsigned short (*bt)[4096], int tid, const u16x8* sb)
{
    #pragma unroll
    for (int q = 0; q < 8; ++q) {
        int id = q * 128 + tid;
        int which = id >> 9, cl = (id >> 2) & 127, pc = id & 3;
        *reinterpret_cast<u16x8*>(&bt[which][cl * 32 + pc * 8]) = sb[q];
    }
}

// ---------------------------- pass 1 (MFMA) ----------------------------
__global__ __launch_bounds__(128, 2) void vq_pass1_mfma(
    const float* __restrict__ z,
    const unsigned short* __restrict__ eh, const unsigned short* __restrict__ el,
    const float* __restrict__ s2g, int* __restrict__ out,
    int* __restrict__ count, int* __restrict__ list, int N)
{
    __shared__ __align__(16) unsigned short Bt[2][2][4096]; // [buf][hi/lo][128x32]

    const int tid  = threadIdx.x;
    const int w    = tid >> 6;
    const int lane = tid & 63;
    const int ll   = lane & 15;
    const int lg   = lane >> 4;                  // 0..3
    const int rowbase = blockIdx.x * 64 + w * 32;

    const int sB    = (ll >> 1) & 3;             // per-lane read swizzle
    const int rdoff = ll * 32 + ((lg ^ sB) << 3);

    f32x4 acc[2][8];
    const f32x4 zero4 = {0.f, 0.f, 0.f, 0.f};
    #pragma unroll
    for (int m = 0; m < 2; ++m)
        #pragma unroll
        for (int n = 0; n < 8; ++n) acc[m][n] = zero4;

    float bv[2][4], sv[2][4];
    int   bk[2][4];
    #pragma unroll
    for (int m = 0; m < 2; ++m)
        #pragma unroll
        for (int j = 0; j < 4; ++j) { bv[m][j] = 3.4e38f; sv[m][j] = 3.4e38f; bk[m][j] = 0; }

    {   // prologue: stage tile 0 into buf 0
        u16x8 sb[8];
        stage_issue(eh, el, 0, 0, tid, sb);
        stage_write(Bt[0], tid, sb);
    }
    __syncthreads();

    for (int t = 0; t < 64; ++t) {
        const int buf = t & 1;
        const int ct = t >> 3, ks = t & 7;

        u16x8 sb[8];
        if (t < 63) stage_issue(eh, el, (t + 1) >> 3, (t + 1) & 7, tid, sb);

        // A-frags: load 8 f32 per (m), convert to bf16 hi/lo in registers
        bf16x8 ah[2], al_[2];
        #pragma unroll
        for (int m = 0; m < 2; ++m) {
            const float* zp = z + (size_t)(rowbase + 16 * m + ll) * DDIM + ks * 32 + lg * 8;
            float4 p0 = *reinterpret_cast<const float4*>(zp);
            float4 p1 = *reinterpret_cast<const float4*>(zp + 4);
            float fv[8] = {p0.x, p0.y, p0.z, p0.w, p1.x, p1.y, p1.z, p1.w};
            #pragma unroll
            for (int e = 0; e < 8; ++e) {
                unsigned short h = f2bf(fv[e]);
                ah[m][e]  = (short)h;
                al_[m][e] = (short)f2bf(fv[e] - bf2f(h));
            }
        }

        #pragma unroll
        for (int n = 0; n < 8; ++n) {
            bf16x8 bh = *reinterpret_cast<const bf16x8*>(&Bt[buf][0][rdoff + n * 512]);
            bf16x8 bl = *reinterpret_cast<const bf16x8*>(&Bt[buf][1][rdoff + n * 512]);
            #pragma unroll
            for (int m = 0; m < 2; ++m) {
                acc[m][n] = __builtin_amdgcn_mfma_f32_16x16x32_bf16(ah[m],  bh, acc[m][n], 0, 0, 0);
                acc[m][n] = __builtin_amdgcn_mfma_f32_16x16x32_bf16(ah[m],  bl, acc[m][n], 0, 0, 0);
                acc[m][n] = __builtin_amdgcn_mfma_f32_16x16x32_bf16(al_[m], bh, acc[m][n], 0, 0, 0);
            }
        }

        if (ks == 7) {          // fold ct-tile into per-row top-2, reset acc
            #pragma unroll
            for (int n = 0; n < 8; ++n) {
                const int c = ct * 128 + n * 16 + ll;
                const float s2v = s2g[c];
                #pragma unroll
                for (int m = 0; m < 2; ++m) {
                    #pragma unroll
                    for (int j = 0; j < 4; ++j) {
                        float v = fmaf(-2.0f, acc[m][n][j], s2v);
                        if (v < bv[m][j] || (v == bv[m][j] && c < bk[m][j])) {
                            sv[m][j] = bv[m][j]; bv[m][j] = v; bk[m][j] = c;
                        } else {
                            sv[m][j] = fminf(sv[m][j], v);
                        }
                    }
                    acc[m][n] = zero4;
                }
            }
        }

        if (t < 63) stage_write(Bt[buf ^ 1], tid, sb);
        __syncthreads();
    }

    // reduce over the 16 lanes holding each row (xor 1,2,4,8 stays in lg-group)
    #pragma unroll
    for (int off = 1; off < 16; off <<= 1) {
        #pragma unroll
        for (int m = 0; m < 2; ++m)
            #pragma unroll
            for (int j = 0; j < 4; ++j) {
                float ob = __shfl_xor(bv[m][j], off, 64);
                int   ok = __shfl_xor(bk[m][j], off, 64);
                float os = __shfl_xor(sv[m][j], off, 64);
                if (ob < bv[m][j] || (ob == bv[m][j] && ok < bk[m][j])) {
                    sv[m][j] = fminf(bv[m][j], os); bv[m][j] = ob; bk[m][j] = ok;
                } else {
                    sv[m][j] = fminf(sv[m][j], ob);
                }
            }
    }

    if (ll == 0) {
        #pragma unroll
        for (int m = 0; m < 2; ++m)
            #pragma unroll
            for (int j = 0; j < 4; ++j) {
                int r = rowbase + 16 * m + lg * 4 + j;   // C/D row = (lane>>4)*4+reg
                if (r < N) {
                    out[r] = bk[m][j];
                    if (sv[m][j] - bv[m][j] <= TAU_MFMA) {
                        int pos = atomicAdd(count, 1);
                        if (pos < LISTCAP) list[pos] = r;
                    }
                }
            }
    }
}

// ------------- pass 1 FALLBACK (round-6 verbatim, fp32 VALU) -------------
__global__ __launch_bounds__(128) void vq_pass1_old(
    const float* __restrict__ z, const float* __restrict__ emb,
    const float* __restrict__ s2g, int* __restrict__ out,
    int* __restrict__ count, int* __restrict__ list, int N)
{
    __shared__ float At[2][32][68];
    __shared__ float Bt[2][32][132];

    const int tid  = threadIdx.x;
    const int ty   = tid >> 4;
    const int tc   = tid & 15;
    const int row0 = blockIdx.x * 64;

    float4 ra[4], rb[8];
    float acc[8][8];
    float bvv[8], svv[8];
    int   bkk[8];
    #pragma unroll
    for (int j = 0; j < 8; ++j) { bvv[j] = 3.4e38f; svv[j] = 3.4e38f; bkk[j] = 0; }

    {
        #pragma unroll
        for (int it = 0; it < 4; ++it) {
            int f4 = it * 128 + tid, r = f4 >> 3, k4 = f4 & 7;
            ra[it] = *reinterpret_cast<const float4*>(z + (size_t)(row0 + r) * DDIM + k4 * 4);
        }
        #pragma unroll
        for (int it = 0; it < 8; ++it) {
            int f4 = it * 128 + tid, c = f4 >> 3, k4 = f4 & 7;
            rb[it] = *reinterpret_cast<const float4*>(emb + (size_t)c * DDIM + k4 * 4);
        }
        #pragma unroll
        for (int it = 0; it < 4; ++it) {
            int f4 = it * 128 + tid, r = f4 >> 3, k4 = f4 & 7;
            At[0][k4 * 4 + 0][r] = ra[it].x; At[0][k4 * 4 + 1][r] = ra[it].y;
            At[0][k4 * 4 + 2][r] = ra[it].z; At[0][k4 * 4 + 3][r] = ra[it].w;
        }
        #pragma unroll
        for (int it = 0; it < 8; ++it) {
            int f4 = it * 128 + tid, c = f4 >> 3, k4 = f4 & 7;
            Bt[0][k4 * 4 + 0][c] = rb[it].x; Bt[0][k4 * 4 + 1][c] = rb[it].y;
            Bt[0][k4 * 4 + 2][c] = rb[it].z; Bt[0][k4 * 4 + 3][c] = rb[it].w;
        }
    }
    __syncthreads();

    for (int t = 0; t < 64; ++t) {
        const int buf = t & 1;
        if (t + 1 < 64) {
            const int ct = (t + 1) >> 3, ks = (t + 1) & 7;
            #pragma unroll
            for (int it = 0; it < 4; ++it) {
                int f4 = it * 128 + tid, r = f4 >> 3, k4 = f4 & 7;
                ra[it] = *reinterpret_cast<const float4*>(
                    z + (size_t)(row0 + r) * DDIM + ks * 32 + k4 * 4);
            }
            #pragma unroll
            for (int it = 0; it < 8; ++it) {
                int f4 = it * 128 + tid, c = f4 >> 3, k4 = f4 & 7;
                rb[it] = *reinterpret_cast<const float4*>(
                    emb + (size_t)(ct * 128 + c) * DDIM + ks * 32 + k4 * 4);
            }
        }
        if ((t & 7) == 0) {
            #pragma unroll
            for (int j = 0; j < 8; ++j)
                #pragma unroll
                for (int i = 0; i < 8; ++i) acc[j][i] = 0.0f;
        }
        #pragma unroll
        for (int kk = 0; kk < 32; ++kk) {
            float a[8], b[8];
            *reinterpret_cast<float4*>(&a[0]) = *reinterpret_cast<const float4*>(&At[buf][kk][ty * 4]);
            *reinterpret_cast<float4*>(&a[4]) = *reinterpret_cast<const float4*>(&At[buf][kk][32 + ty * 4]);
            *reinterpret_cast<float4*>(&b[0]) = *reinterpret_cast<const float4*>(&Bt[buf][kk][tc * 4]);
            *reinterpret_cast<float4*>(&b[4]) = *reinterpret_cast<const float4*>(&Bt[buf][kk][64 + tc * 4]);
            #pragma unroll
            for (int j = 0; j < 8; ++j)
                #pragma unroll
                for (int i = 0; i < 8; ++i) acc[j][i] = fmaf(a[j], b[i], acc[j][i]);
        }
        if ((t & 7) == 7) {
            const int ct = t >> 3;
            #pragma unroll
            for (int i = 0; i < 8; ++i) {
                const int c = ct * 128 + (i < 4 ? tc * 4 + i : 64 + tc * 4 + (i - 4));
                const float s2v = s2g[c];
                #pragma unroll
                for (int j = 0; j < 8; ++j) {
                    float v = fmaf(-2.0f, acc[j][i], s2v);
                    if (v < bvv[j] || (v == bvv[j] && c < bkk[j])) {
                        svv[j] = bvv[j]; bvv[j] = v; bkk[j] = c;
                    } else svv[j] = fminf(svv[j], v);
                }
            }
        }
        if (t + 1 < 64) {
            const int nb = buf ^ 1;
            #pragma unroll
            for (int it = 0; it < 4; ++it) {
                int f4 = it * 128 + tid, r = f4 >> 3, k4 = f4 & 7;
                At[nb][k4 * 4 + 0][r] = ra[it].x; At[nb][k4 * 4 + 1][r] = ra[it].y;
                At[nb][k4 * 4 + 2][r] = ra[it].z; At[nb][k4 * 4 + 3][r] = ra[it].w;
            }
            #pragma unroll
            for (int it = 0; it < 8; ++it) {
                int f4 = it * 128 + tid, c = f4 >> 3, k4 = f4 & 7;
                Bt[nb][k4 * 4 + 0][c] = rb[it].x; Bt[nb][k4 * 4 + 1][c] = rb[it].y;
                Bt[nb][k4 * 4 + 2][c] = rb[it].z; Bt[nb][k4 * 4 + 3][c] = rb[it].w;
            }
        }
        __syncthreads();
    }
    #pragma unroll
    for (int off = 1; off < 16; off <<= 1) {
        #pragma unroll
        for (int j = 0; j < 8; ++j) {
            float ob = __shfl_xor(bvv[j], off, 64);
            int   ok = __shfl_xor(bkk[j], off, 64);
            float os = __shfl_xor(svv[j], off, 64);
            if (ob < bvv[j] || (ob == bvv[j] && ok < bkk[j])) {
                svv[j] = fminf(bvv[j], os); bvv[j] = ob; bkk[j] = ok;
            } else svv[j] = fminf(svv[j], ob);
        }
    }
    if (tc == 0) {
        #pragma unroll
        for (int j = 0; j < 8; ++j) {
            int r = row0 + (j < 4 ? ty * 4 + j : 32 + ty * 4 + (j - 4));
            if (r < N) {
                out[r] = bkk[j];
                if (svv[j] - bvv[j] <= TAU_OLD) {
                    int pos = atomicAdd(count, 1);
                    if (pos < LISTCAP) list[pos] = r;
                }
            }
        }
    }
}

// ------- pass 2: exact rescore, one block per flagged row (LOCKED) -------
__global__ __launch_bounds__(256) void vq_pass2(
    const float* __restrict__ z, const float* __restrict__ emb,
    const float* __restrict__ s2g, const int* __restrict__ count,
    const int* __restrict__ list, int* __restrict__ out)
{
#pragma clang fp contract(off)
    __shared__ float zrow[DDIM];
    __shared__ float s1sh;
    __shared__ float bvw[4];
    __shared__ int   bkw[4];

    const int tid  = threadIdx.x;
    const int lane = tid & 63;
    const int wid  = tid >> 6;
    int cnt = *count; if (cnt > LISTCAP) cnt = LISTCAP;

    for (int idx = blockIdx.x; idx < cnt; idx += gridDim.x) {
        const int row = list[idx];

        if (tid < 64)
            *reinterpret_cast<float4*>(&zrow[tid * 4]) =
                *reinterpret_cast<const float4*>(z + (size_t)row * DDIM + tid * 4);
        __syncthreads();
        if (tid == 0) s1sh = block128_sq(zrow) + block128_sq(zrow + 128);
        __syncthreads();
        const float s1 = s1sh;

        float bestv = 3.4e38f;
        int   bestk = 0;
        #pragma unroll
        for (int i = 0; i < 4; ++i) {
            const int c = tid * 4 + i;
            const float* __restrict__ e = emb + (size_t)c * DDIM;
            double dot = 0.0;
            #pragma unroll 8
            for (int d4 = 0; d4 < DDIM / 4; ++d4) {
                float4 ev = *reinterpret_cast<const float4*>(e + d4 * 4);
                const float4 zv = *reinterpret_cast<const float4*>(&zrow[d4 * 4]);
                dot = fma((double)zv.x, (double)ev.x, dot);
                dot = fma((double)zv.y, (double)ev.y, dot);
                dot = fma((double)zv.z, (double)ev.z, dot);
                dot = fma((double)zv.w, (double)ev.w, dot);
            }
            float twog = 2.0f * (float)dot;
            float t1   = s1 - twog;
            float dv   = t1 + s2g[c];
            if (dv < bestv || (dv == bestv && c < bestk)) { bestv = dv; bestk = c; }
        }

        #pragma unroll
        for (int off = 1; off < 64; off <<= 1) {
            float ov = __shfl_xor(bestv, off, 64);
            int   ok = __shfl_xor(bestk, off, 64);
            if (ov < bestv || (ov == bestv && ok < bestk)) { bestv = ov; bestk = ok; }
        }
        if (lane == 0) { bvw[wid] = bestv; bkw[wid] = bestk; }
        __syncthreads();
        if (tid == 0) {
            float bb = bvw[0]; int kb = bkw[0];
            #pragma unroll
            for (int ww = 1; ww < 4; ++ww)
                if (bvw[ww] < bb || (bvw[ww] == bb && bkw[ww] < kb)) { bb = bvw[ww]; kb = bkw[ww]; }
            out[row] = kb;
        }
        __syncthreads();
    }
}

extern "C" void kernel_launch(void* const* d_in, const int* in_sizes, int n_in,
                              void* d_out, int out_size, void* d_ws, size_t ws_size,
                              hipStream_t stream) {
    const float* z   = (const float*)d_in[0];
    const float* emb = (const float*)d_in[1];
    int*   out   = (int*)d_out;
    float* s2    = (float*)d_ws;                                   // 4 KB
    int*   count = (int*)((char*)d_ws + 4096);
    int*   list  = (int*)((char*)d_ws + 4224);                     // 64 KB
    const int N = in_sizes[0] / DDIM;                              // 32768

    vq_s2_kernel<<<dim3((KCODES + 255) / 256), dim3(256), 0, stream>>>(emb, s2, count);

    const size_t WS_NEEDED = 131072 + 2 * 524288;                  // ~1.15 MB
    if (ws_size >= WS_NEEDED) {
        unsigned short* eh = (unsigned short*)((char*)d_ws + 131072);
        unsigned short* el = (unsigned short*)((char*)d_ws + 131072 + 524288);
        vq_convert<<<dim3(KCODES * DDIM / 8 / 256), dim3(256), 0, stream>>>(emb, eh, el);
        vq_pass1_mfma<<<dim3(N / 64), dim3(128), 0, stream>>>(z, eh, el, s2, out, count, list, N);
    } else {
        vq_pass1_old<<<dim3(N / 64), dim3(128), 0, stream>>>(z, emb, s2, out, count, list, N);
    }
    vq_pass2<<<dim3(2048), dim3(256), 0, stream>>>(z, emb, s2, count, list, out);
}